// Round 6
// baseline (405.680 us; speedup 1.0000x reference)
//
#include <hip/hip_runtime.h>
#include <math.h>

// LIF first-spike time, closed form:
//   a = 0.8 ; n = max(ceil((log2(I-1)-log2(I))/log2(a)), 1) ; t = 0.01*n
//   I <= 1 -> finite sentinel (ref has +inf there; harness needs NO NaN/inf).
//
// R5 post-mortem: kernel ~143us with VALU ~15us (chip-wide) and memory floor
// ~61-85us -> NEITHER pipe saturated: structure/latency-bound. One float4 per
// thread = one dependent load->use chain per wave, zero in-wave MLP.
// v6: 16 elems/thread, 4 coalesced float4 loads issued back-to-back (4 KB of
// outstanding reads per wave before first use), compute 16, 4 cached stores
// (NT reverted: R5 showed it cost ~10us - loses L2 writeback batching).
// 32-bit addressing throughout (byte offsets < 2^31).

#define SENTINEL_F 1.0e30f
#define C_NR (-3.1062837f) /* 1 / log2(0.8f) */

typedef float vfloat4 __attribute__((ext_vector_type(4)));

__device__ __forceinline__ float spike_time_min(float cur) {
    float la = __log2f(cur - 1.0f);   // v_log_f32; NaN (cur<1) / -inf (cur==1)
    float lb = __log2f(cur);          // v_log_f32
    float nr = fmaf(la, C_NR, lb * (-C_NR));    // mul + fma
    float nn = fmaxf(ceilf(nr), 1.0f);          // IEEE v_max eats NaN -> cur>1
    return (cur > 1.0f) ? nn * 0.01f : SENTINEL_F;  // predicate is load-bearing
}

__device__ __forceinline__ vfloat4 spike_time_v4(vfloat4 v) {
    vfloat4 r;
    r.x = spike_time_min(v.x);
    r.y = spike_time_min(v.y);
    r.z = spike_time_min(v.z);
    r.w = spike_time_min(v.w);
    return r;
}

// Main kernel: each 256-thread block covers 1024 consecutive float4s as
// 4 wave-coalesced chunks of 256. Requires nvec % 1024 == 0 (launcher
// guarantees; tail kernel handles the rest).
__global__ __launch_bounds__(256) void lif_spike_v6(const vfloat4* __restrict__ in4,
                                                    vfloat4* __restrict__ out4) {
    const int base = blockIdx.x * 1024 + threadIdx.x;
    // 4 independent loads, back-to-back issue -> 4 outstanding per wave
    vfloat4 v0 = in4[base];
    vfloat4 v1 = in4[base + 256];
    vfloat4 v2 = in4[base + 512];
    vfloat4 v3 = in4[base + 768];
    vfloat4 r0 = spike_time_v4(v0);
    vfloat4 r1 = spike_time_v4(v1);
    vfloat4 r2 = spike_time_v4(v2);
    vfloat4 r3 = spike_time_v4(v3);
    out4[base]       = r0;
    out4[base + 256] = r1;
    out4[base + 512] = r2;
    out4[base + 768] = r3;
}

// Tail: scalar grid-stride over [start, n). Only launched when needed.
__global__ __launch_bounds__(256) void lif_spike_v6_tail(const float* __restrict__ in,
                                                         float* __restrict__ out,
                                                         int start, int n) {
    int i = start + blockIdx.x * blockDim.x + threadIdx.x;
    const int stride = gridDim.x * blockDim.x;
    for (; i < n; i += stride) {
        out[i] = spike_time_min(in[i]);
    }
}

extern "C" void kernel_launch(void* const* d_in, const int* in_sizes, int n_in,
                              void* d_out, int out_size, void* d_ws, size_t ws_size,
                              hipStream_t stream) {
    const float* in = (const float*)d_in[0];
    float* out = (float*)d_out;
    const int n = in_sizes[0]; // 64,000,000 fp32

    const bool aligned16 = ((((uintptr_t)in) | ((uintptr_t)out)) & 0xF) == 0;

    int done = 0;
    if (aligned16) {
        const int nvec = n >> 2;                // float4 count
        const int nblk = nvec / 1024;           // full blocks (15625 for 64M)
        if (nblk > 0) {
            lif_spike_v6<<<nblk, 256, 0, stream>>>((const vfloat4*)in,
                                                   (vfloat4*)out);
            done = nblk * 1024 * 4;             // elements covered
        }
    }
    if (done < n) {
        const int rem = n - done;
        int grid = (rem + 255) / 256;
        if (grid > 4096) grid = 4096;
        lif_spike_v6_tail<<<grid, 256, 0, stream>>>(in, out, done, n);
    }
}